// Round 1
// baseline (368.367 us; speedup 1.0000x reference)
//
#include <hip/hip_runtime.h>

// Problem constants (from reference): B=1024, D=64, M=3, C=16384
#define B_  1024
#define D_  64
#define M_  3
#define C_  16384
#define CT  128    // c-rows per block in the LSE-partial kernel

// ---------------------------------------------------------------------------
// Workspace layout (floats):
//   ws[0]                      : global scalar accumulator (t + t_I terms)
//   ws[16 .. 16+M*B)           : branch-0 logsum  (M*B = 3072)
//   ws[16+M*B .. 16+2*M*B)     : branch-1 logsum
// total 16 + 6144 floats; we zero the first 8192 floats.
// ---------------------------------------------------------------------------

__global__ __launch_bounds__(256) void zero_ws(float* __restrict__ ws) {
    ws[blockIdx.x * 256 + threadIdx.x] = 0.0f;
}

// Partial sum over a c-tile of exp((cen[m,c] . f[b]) / conc[m,c]).
// All threads in the block walk the SAME c (centroid row is wave-uniform ->
// scalar loads, SGPR operand in the FMA). Each thread owns one b, with
// f[b][0..63] resident in 64 VGPRs.
__global__ __launch_bounds__(256) void logsum_partial(
    const float* __restrict__ feats,   // [B, D]
    const float* __restrict__ cen,     // [M, C, D]
    const float* __restrict__ conc,    // [M, C]
    float* __restrict__ wsum)          // [M * B]
{
    const int m  = blockIdx.y;
    const int c0 = blockIdx.x * CT;
    const int b  = blockIdx.z * 256 + threadIdx.x;

    // Load this thread's feature row into registers (16 x dwordx4).
    float fr[D_];
    const float* frow = feats + (size_t)b * D_;
#pragma unroll
    for (int d = 0; d < D_; d += 4) {
        const float4 v = *reinterpret_cast<const float4*>(frow + d);
        fr[d + 0] = v.x; fr[d + 1] = v.y; fr[d + 2] = v.z; fr[d + 3] = v.w;
    }

    const float* crow = cen  + ((size_t)m * C_ + c0) * D_;
    const float* krow = conc +  (size_t)m * C_ + c0;

    float sum = 0.0f;
    for (int c = 0; c < CT; ++c) {
        const float  ic = 1.0f / krow[c];                 // uniform
        const float* cr = crow + (size_t)c * D_;          // uniform row
        float a0 = 0.f, a1 = 0.f, a2 = 0.f, a3 = 0.f;     // 4 chains for ILP
#pragma unroll
        for (int d = 0; d < D_; d += 4) {
            a0 = fmaf(cr[d + 0], fr[d + 0], a0);
            a1 = fmaf(cr[d + 1], fr[d + 1], a1);
            a2 = fmaf(cr[d + 2], fr[d + 2], a2);
            a3 = fmaf(cr[d + 3], fr[d + 3], a3);
        }
        const float dot = (a0 + a1) + (a2 + a3);
        sum += __expf(dot * ic);
    }
    atomicAdd(&wsum[m * B_ + b], sum);
}

// Per (m,b): term = pos_logit - log(logsum).  Wave-reduce then one atomic.
__global__ __launch_bounds__(256) void finish_branch(
    const float* __restrict__ feats,   // [B, D]
    const float* __restrict__ cen,     // [M, C, D]
    const float* __restrict__ conc,    // [M, C]
    const int*   __restrict__ lab,     // [M, B]
    const float* __restrict__ wsum,    // [M * B]
    float* __restrict__ accum)         // scalar
{
    const int idx = blockIdx.x * 256 + threadIdx.x;   // 0 .. M*B-1
    const int m = idx / B_;
    const int b = idx - m * B_;
    const int c = lab[idx];

    const float* cr   = cen + ((size_t)m * C_ + c) * D_;
    const float* frow = feats + (size_t)b * D_;
    float a0 = 0.f, a1 = 0.f, a2 = 0.f, a3 = 0.f;
#pragma unroll
    for (int d = 0; d < D_; d += 4) {
        a0 = fmaf(cr[d + 0], frow[d + 0], a0);
        a1 = fmaf(cr[d + 1], frow[d + 1], a1);
        a2 = fmaf(cr[d + 2], frow[d + 2], a2);
        a3 = fmaf(cr[d + 3], frow[d + 3], a3);
    }
    const float logit = ((a0 + a1) + (a2 + a3)) / conc[(size_t)m * C_ + c];
    float term = logit - __logf(wsum[idx]);

    // 64-lane wave reduce
#pragma unroll
    for (int off = 32; off > 0; off >>= 1)
        term += __shfl_down(term, off);
    if ((threadIdx.x & 63) == 0)
        atomicAdd(accum, term);
}

__global__ void finalize(const float* __restrict__ accum,
                         const int*   __restrict__ lb,
                         float* __restrict__ out)
{
    out[0] = (1.0f / (float)B_) * (float)lb[0] * (-1.0f / (float)M_) * 0.5f
             * accum[0];
}

extern "C" void kernel_launch(void* const* d_in, const int* in_sizes, int n_in,
                              void* d_out, int out_size, void* d_ws, size_t ws_size,
                              hipStream_t stream) {
    const float* f      = (const float*)d_in[0];   // features      [B,D]
    const float* f_I    = (const float*)d_in[1];   // features_I    [B,D]
    const float* cen    = (const float*)d_in[2];   // M_kmeans      [M,C,D]
    const float* cen_I  = (const float*)d_in[3];   // M_kmeans_I    [M,C,D]
    const float* conc   = (const float*)d_in[4];   // concentrations   [M,C]
    const float* conc_I = (const float*)d_in[5];   // concentrations_I [M,C]
    const int*   lab    = (const int*)d_in[6];     // labels        [M,B]
    const int*   lab_I  = (const int*)d_in[7];     // labels_I      [M,B]
    const int*   lb     = (const int*)d_in[8];     // scalar

    float* ws    = (float*)d_ws;
    float* accum = ws;                 // ws[0]
    float* wsum0 = ws + 16;            // branch 0: cen   x f_I
    float* wsum1 = ws + 16 + M_ * B_;  // branch 1: cen_I x f
    float* out   = (float*)d_out;

    zero_ws<<<32, 256, 0, stream>>>(ws);   // zeros first 8192 floats

    dim3 g1(C_ / CT, M_, B_ / 256);
    logsum_partial<<<g1, 256, 0, stream>>>(f_I, cen,   conc,   wsum0);
    logsum_partial<<<g1, 256, 0, stream>>>(f,   cen_I, conc_I, wsum1);

    finish_branch<<<(M_ * B_) / 256, 256, 0, stream>>>(f_I, cen,   conc,   lab,   wsum0, accum);
    finish_branch<<<(M_ * B_) / 256, 256, 0, stream>>>(f,   cen_I, conc_I, lab_I, wsum1, accum);

    finalize<<<1, 1, 0, stream>>>(accum, lb, out);
}

// Round 2
// 176.643 us; speedup vs baseline: 2.0854x; 2.0854x over previous
//
#include <hip/hip_runtime.h>

// Problem constants: B=1024, D=64, M=3, C=16384
#define B_  1024
#define D_  64
#define M_  3
#define C_  16384

typedef __attribute__((ext_vector_type(8))) short bf16x8;   // 8 bf16 (4 VGPRs)
typedef __attribute__((ext_vector_type(4))) float f32x4;    // MFMA acc

// float -> bf16 bits, round-to-nearest-even
__device__ __forceinline__ unsigned short f2bf(float x) {
    union { float f; unsigned u; } v; v.f = x;
    unsigned r = v.u + 0x7FFFu + ((v.u >> 16) & 1u);
    return (unsigned short)(r >> 16);
}

// ---------------------------------------------------------------------------
// Workspace (floats):
//   ws[0]                : scalar accumulator
//   ws[16   .. 3088)     : wsum0 [M*B]
//   ws[3088 .. 6160)     : wsum1 [M*B]
//   ws[6160 .. 38928)    : fb0   (features_I as bf16, [B][D] ushort)
//   ws[38928.. 71696)    : fb1   (features   as bf16)
// ---------------------------------------------------------------------------

__global__ __launch_bounds__(256) void zero_ws(float* __restrict__ ws) {
    int i = blockIdx.x * 256 + threadIdx.x;   // grid 25 -> 6400 >= 6160
    if (i < 6160) ws[i] = 0.0f;
}

__global__ __launch_bounds__(256) void prep_features(
    const float* __restrict__ f, const float* __restrict__ f_I,
    unsigned short* __restrict__ fb0, unsigned short* __restrict__ fb1) {
    int i = blockIdx.x * 256 + threadIdx.x;   // grid 256 -> 65536 = B*D
    fb0[i] = f2bf(f_I[i]);   // branch 0 uses features_I
    fb1[i] = f2bf(f[i]);     // branch 1 uses features
}

// One launch, both branches (z). Per wave: 32 c-rows, loop over all 64
// b-tiles. A (centroid) fragments live in registers; cen is read from HBM
// exactly once. Fused epilogue: exp(dot * 1/conc), reduce over the wave's
// 32 c-rows, one 16-lane atomicAdd per b-tile.
__global__ __launch_bounds__(256) void lse_mfma(
    const float* __restrict__ cen0, const float* __restrict__ cen1,
    const unsigned short* __restrict__ fbr0, const unsigned short* __restrict__ fbr1,
    const float* __restrict__ conc0, const float* __restrict__ conc1,
    float* __restrict__ wsum0, float* __restrict__ wsum1)
{
    const int branch = blockIdx.z;
    const float* __restrict__ cen  = branch ? cen1  : cen0;
    const unsigned short* __restrict__ fb = branch ? fbr1 : fbr0;
    const float* __restrict__ conc = branch ? conc1 : conc0;
    float* __restrict__ wsum       = branch ? wsum1 : wsum0;

    const int m    = blockIdx.y;
    const int wave = threadIdx.x >> 6;
    const int lane = threadIdx.x & 63;
    const int lrow = lane & 15;
    const int lk   = lane >> 4;                    // 0..3 (k-group)
    const int cbase = blockIdx.x * 128 + wave * 32;

    // --- A fragments: 2 row-tiles x 2 K-halves, fp32 -> bf16 in regs ------
    bf16x8 af[2][2];
#pragma unroll
    for (int t = 0; t < 2; ++t) {
        const int crow = cbase + t * 16 + lrow;
        const float* cp = cen + ((size_t)(m * C_ + crow)) * D_;
#pragma unroll
        for (int kk = 0; kk < 2; ++kk) {
            const int d = kk * 32 + lk * 8;
            const float4 x = *reinterpret_cast<const float4*>(cp + d);
            const float4 y = *reinterpret_cast<const float4*>(cp + d + 4);
            bf16x8 a;
            a[0] = (short)f2bf(x.x); a[1] = (short)f2bf(x.y);
            a[2] = (short)f2bf(x.z); a[3] = (short)f2bf(x.w);
            a[4] = (short)f2bf(y.x); a[5] = (short)f2bf(y.y);
            a[6] = (short)f2bf(y.z); a[7] = (short)f2bf(y.w);
            af[t][kk] = a;
        }
    }

    // --- 1/conc for this lane's 8 accumulator rows -------------------------
    // C/D layout (m89-verified): col = lane&15, row = (lane>>4)*4 + j
    float ic[2][4];
#pragma unroll
    for (int t = 0; t < 2; ++t)
#pragma unroll
        for (int j = 0; j < 4; ++j)
            ic[t][j] = 1.0f / conc[m * C_ + cbase + t * 16 + lk * 4 + j];

    float* __restrict__ wsm = wsum + m * B_;

    for (int bt = 0; bt < B_ / 16; ++bt) {
        const int b0 = bt * 16;
        const unsigned short* fp = fb + (size_t)(b0 + lrow) * D_ + lk * 8;
        const bf16x8 bf0 = *reinterpret_cast<const bf16x8*>(fp);
        const bf16x8 bf1 = *reinterpret_cast<const bf16x8*>(fp + 32);

        f32x4 acc0 = {0.f, 0.f, 0.f, 0.f};
        f32x4 acc1 = {0.f, 0.f, 0.f, 0.f};
        acc0 = __builtin_amdgcn_mfma_f32_16x16x32_bf16(af[0][0], bf0, acc0, 0, 0, 0);
        acc0 = __builtin_amdgcn_mfma_f32_16x16x32_bf16(af[0][1], bf1, acc0, 0, 0, 0);
        acc1 = __builtin_amdgcn_mfma_f32_16x16x32_bf16(af[1][0], bf0, acc1, 0, 0, 0);
        acc1 = __builtin_amdgcn_mfma_f32_16x16x32_bf16(af[1][1], bf1, acc1, 0, 0, 0);

        float s = 0.0f;
#pragma unroll
        for (int j = 0; j < 4; ++j) {
            s += __expf(acc0[j] * ic[0][j]);
            s += __expf(acc1[j] * ic[1][j]);
        }
        // reduce across the 4 k-groups (rows) -> total over 32 c-rows per col
        s += __shfl_xor(s, 16);
        s += __shfl_xor(s, 32);
        if (lane < 16) atomicAdd(&wsm[b0 + lane], s);
    }
}

// Per (m,b): term = pos_logit - log(logsum). Wave-reduce, one atomic/wave.
__global__ __launch_bounds__(256) void finish_branch(
    const float* __restrict__ feats, const float* __restrict__ cen,
    const float* __restrict__ conc,  const int* __restrict__ lab,
    const float* __restrict__ wsum,  float* __restrict__ accum)
{
    const int idx = blockIdx.x * 256 + threadIdx.x;   // 0 .. M*B-1
    const int m = idx / B_;
    const int b = idx - m * B_;
    const int c = lab[idx];

    const float* cr   = cen + ((size_t)(m * C_ + c)) * D_;
    const float* frow = feats + (size_t)b * D_;
    float a0 = 0.f, a1 = 0.f, a2 = 0.f, a3 = 0.f;
#pragma unroll
    for (int d = 0; d < D_; d += 4) {
        a0 = fmaf(cr[d + 0], frow[d + 0], a0);
        a1 = fmaf(cr[d + 1], frow[d + 1], a1);
        a2 = fmaf(cr[d + 2], frow[d + 2], a2);
        a3 = fmaf(cr[d + 3], frow[d + 3], a3);
    }
    const float logit = ((a0 + a1) + (a2 + a3)) / conc[(size_t)m * C_ + c];
    float term = logit - __logf(wsum[idx]);

#pragma unroll
    for (int off = 32; off > 0; off >>= 1)
        term += __shfl_down(term, off);
    if ((threadIdx.x & 63) == 0)
        atomicAdd(accum, term);
}

__global__ void finalize(const float* __restrict__ accum,
                         const int* __restrict__ lb,
                         float* __restrict__ out)
{
    out[0] = (1.0f / (float)B_) * (float)lb[0] * (-1.0f / (float)M_) * 0.5f
             * accum[0];
}

extern "C" void kernel_launch(void* const* d_in, const int* in_sizes, int n_in,
                              void* d_out, int out_size, void* d_ws, size_t ws_size,
                              hipStream_t stream) {
    const float* f      = (const float*)d_in[0];
    const float* f_I    = (const float*)d_in[1];
    const float* cen    = (const float*)d_in[2];
    const float* cen_I  = (const float*)d_in[3];
    const float* conc   = (const float*)d_in[4];
    const float* conc_I = (const float*)d_in[5];
    const int*   lab    = (const int*)d_in[6];
    const int*   lab_I  = (const int*)d_in[7];
    const int*   lb     = (const int*)d_in[8];

    float* ws    = (float*)d_ws;
    float* accum = ws;
    float* wsum0 = ws + 16;
    float* wsum1 = ws + 16 + M_ * B_;
    unsigned short* fb0 = (unsigned short*)(ws + 6160);
    unsigned short* fb1 = (unsigned short*)(ws + 38928);
    float* out = (float*)d_out;

    zero_ws<<<25, 256, 0, stream>>>(ws);
    prep_features<<<(B_ * D_) / 256, 256, 0, stream>>>(f, f_I, fb0, fb1);

    dim3 g(C_ / 128, M_, 2);
    lse_mfma<<<g, 256, 0, stream>>>(cen, cen_I, fb0, fb1, conc, conc_I,
                                    wsum0, wsum1);

    finish_branch<<<(M_ * B_) / 256, 256, 0, stream>>>(f_I, cen,   conc,   lab,   wsum0, accum);
    finish_branch<<<(M_ * B_) / 256, 256, 0, stream>>>(f,   cen_I, conc_I, lab_I, wsum1, accum);
    finalize<<<1, 1, 0, stream>>>(accum, lb, out);
}